// Round 12
// baseline (95.389 us; speedup 1.0000x reference)
//
#include <hip/hip_runtime.h>
#include <math.h>

#define B_BAGS 512
#define N_REL  128
#define D_DIM  768
#define NCHUNK 4       // split-K chunks (6 gs = 192 k each)

typedef __attribute__((ext_vector_type(8))) short  bf16x8;
typedef __attribute__((ext_vector_type(4))) float  f32x4;

// pack truncated-bf16 of (f0,f1) -> one uint (low short = bf16(f0))
__device__ inline unsigned pack_hi(float f0, float f1) {
    return __builtin_amdgcn_perm(__float_as_uint(f1), __float_as_uint(f0), 0x07060302u);
}
__device__ inline float trunc_res(float f) {   // f - bf16_trunc(f)
    return f - __uint_as_float(__float_as_uint(f) & 0xFFFF0000u);
}

// ---------------------------------------------------------------------------
// K1: fragment-ordered bf16 hi/lo of W (validated r2-r11).
// uint index = ((s*8 + tile)*2 + p)*256 + lane*4 + 0..3
// Element: n = tile*16 + (lane&15), k = s*32 + (lane>>4)*8 + j.
// ---------------------------------------------------------------------------
__global__ void build_bfrag(const float* __restrict__ W, unsigned* __restrict__ Bfrag) {
    int flat = blockIdx.x * 256 + threadIdx.x;     // 0..12287
    int lane = flat & 63;
    int tile = (flat >> 6) & 7;
    int s    = flat >> 9;                          // 0..23
    int n  = tile * 16 + (lane & 15);
    int k0 = s * 32 + (lane >> 4) * 8;
    const float* src = &W[n * D_DIM + k0];
    float f[8];
    #pragma unroll
    for (int j = 0; j < 8; ++j) f[j] = src[j];
    unsigned hi[4], lo[4];
    #pragma unroll
    for (int q = 0; q < 4; ++q) {
        hi[q] = pack_hi(f[2*q], f[2*q+1]);
        lo[q] = pack_hi(trunc_res(f[2*q]), trunc_res(f[2*q+1]));
    }
    unsigned base = (unsigned)(((s * 8 + tile) * 2) * 64 + lane) * 4;
    *(uint4*)&Bfrag[base]          = make_uint4(hi[0], hi[1], hi[2], hi[3]);
    *(uint4*)&Bfrag[base + 64 * 4] = make_uint4(lo[0], lo[1], lo[2], lo[3]);
}

// ---------------------------------------------------------------------------
// K2: dense H = rep @ W^T, 32-row strips x split-K/4. grid (S, 4), 256 thr
// = 4 waves; wave wv owns n-tile pair {2wv, 2wv+1} x BOTH m-tiles (12 MFMA
// per gs on 4 B-loads -> 3:1). A staged per-64-k stage into LDS as packed
// bf16 hi/lo (stride-36 pad). B direct from L2-resident Bfrag (validated).
// Plain stores to partial Hp[chunk] (r9-validated pattern).
// ~1052 blocks at 4 blocks/CU -> ~16 waves/CU.
// ---------------------------------------------------------------------------
__global__ __launch_bounds__(256, 4) void h_gemm(
    const float*    __restrict__ rep,
    const unsigned* __restrict__ Bfrag,
    float*          __restrict__ Hp,     // NCHUNK buffers of hstride floats
    int nsum, int hstride)
{
    __shared__ unsigned As[2][32][36];   // [plane][row][32+4 pad]  9.2 KB

    const int t     = threadIdx.x;
    const int strip = blockIdx.x;
    const int chunk = blockIdx.y;        // K-quarter (6 gs each)

    const int wv   = t >> 6;             // 0..3 = n-tile pair {2wv, 2wv+1}
    const int lane = t & 63;
    const int nl15 = lane & 15;
    const int lg   = lane >> 4;

    // staging: thread covers row t>>3, 8 k-cols at (t&7)*8 of each 64-k stage
    const int srow = t >> 3;
    const int scq  = t & 7;
    int grow = strip * 32 + srow;
    grow = (grow > nsum - 1) ? (nsum - 1) : grow;
    const float* srp = &rep[(size_t)grow * D_DIM + chunk * 192 + scq * 8];

    f32x4 acc[2][2][2];   // [mt][ntl][0]=hi*hi, [1]=hi*lo+lo*hi
    #pragma unroll
    for (int mt = 0; mt < 2; ++mt)
        #pragma unroll
        for (int ntl = 0; ntl < 2; ++ntl) {
            acc[mt][ntl][0] = f32x4{0.f, 0.f, 0.f, 0.f};
            acc[mt][ntl][1] = f32x4{0.f, 0.f, 0.f, 0.f};
        }

    #pragma unroll
    for (int st = 0; st < 3; ++st) {
        if (st) __syncthreads();         // previous stage's reads complete
        // ---- stage 64 k-cols: fp32 -> bf16 hi/lo into LDS ----
        {
            const float4 v0 = *(const float4*)&srp[st * 64];
            const float4 v1 = *(const float4*)&srp[st * 64 + 4];
            const float f[8] = {v0.x, v0.y, v0.z, v0.w, v1.x, v1.y, v1.z, v1.w};
            unsigned hi[4], lo[4];
            #pragma unroll
            for (int w = 0; w < 4; ++w) {
                hi[w] = pack_hi(f[2*w], f[2*w+1]);
                lo[w] = pack_hi(trunc_res(f[2*w]), trunc_res(f[2*w+1]));
            }
            *(uint4*)&As[0][srow][scq * 4] = make_uint4(hi[0], hi[1], hi[2], hi[3]);
            *(uint4*)&As[1][srow][scq * 4] = make_uint4(lo[0], lo[1], lo[2], lo[3]);
        }
        __syncthreads();

        // ---- compute 2 gs of this stage ----
        #pragma unroll
        for (int g = 0; g < 2; ++g) {
            const int gs = chunk * 6 + st * 2 + g;        // global K-step 0..23
            bf16x8 ah[2], al[2];
            #pragma unroll
            for (int mt = 0; mt < 2; ++mt) {
                const int arow = mt * 16 + nl15;
                ah[mt] = *(const bf16x8*)&As[0][arow][g * 16 + lg * 4];
                al[mt] = *(const bf16x8*)&As[1][arow][g * 16 + lg * 4];
            }
            #pragma unroll
            for (int ntl = 0; ntl < 2; ++ntl) {
                const int nt = wv * 2 + ntl;
                const bf16x8 bh = *(const bf16x8*)&Bfrag[((gs * 8 + nt) * 2 + 0) * 256 + lane * 4];
                const bf16x8 bl = *(const bf16x8*)&Bfrag[((gs * 8 + nt) * 2 + 1) * 256 + lane * 4];
                #pragma unroll
                for (int mt = 0; mt < 2; ++mt) {
                    acc[mt][ntl][0] = __builtin_amdgcn_mfma_f32_16x16x32_bf16(ah[mt], bh, acc[mt][ntl][0], 0, 0, 0);
                    acc[mt][ntl][1] = __builtin_amdgcn_mfma_f32_16x16x32_bf16(ah[mt], bl, acc[mt][ntl][1], 0, 0, 0);
                    acc[mt][ntl][1] = __builtin_amdgcn_mfma_f32_16x16x32_bf16(al[mt], bh, acc[mt][ntl][1], 0, 0, 0);
                }
            }
        }
    }

    // ---- epilogue: C/D layout col=lane&15, row=(lane>>4)*4+r (validated) ----
    float* H = Hp + (size_t)chunk * hstride;
    #pragma unroll
    for (int mt = 0; mt < 2; ++mt) {
        const int rowb = strip * 32 + mt * 16 + lg * 4;
        #pragma unroll
        for (int ntl = 0; ntl < 2; ++ntl) {
            const int col = (wv * 2 + ntl) * 16 + nl15;
            #pragma unroll
            for (int r = 0; r < 4; ++r)
                H[(size_t)(rowb + r) * N_REL + col] = acc[mt][ntl][0][r] + acc[mt][ntl][1][r];
        }
    }
}

// ---------------------------------------------------------------------------
// K3: per-bag output (r9-r11-validated). 512 thr = 8 waves; wave T = wv owns
// n-tile T. gv = sum of 4 Hp partials in C/D-register positions, then:
// in-register masked softmax over m, frag scatter, 24-MFMA phase 2,
// in-register row softmax over k, diagonal -> out.
// ---------------------------------------------------------------------------
__global__ __launch_bounds__(512, 2) void bag_out(
    const float* __restrict__ Hp, int hstride,
    const float* __restrict__ bias,
    const int*   __restrict__ scope,
    float*       __restrict__ out,
    int nsum)
{
    __shared__ unsigned Gfrag[8 * 2 * 64 * 4];    // 16 KB [tile][p][lane][4]
    __shared__ unsigned SMfrag[8 * 2 * 64 * 4];   // 16 KB

    const int t = threadIdx.x;
    const int b = blockIdx.x;
    const int start = scope[2 * b];
    const int size  = scope[2 * b + 1] - start;   // in [8, 25)

    const int wv   = t >> 6;
    const int lane = t & 63;
    const int nl15 = lane & 15;
    const int lg   = lane >> 4;
    const int T    = wv;

    // ---- gv: sum of 4 partials in C/D positions ----
    float gv[2][4], smv[2][4];
    #pragma unroll
    for (int mt = 0; mt < 2; ++mt)
        #pragma unroll
        for (int r = 0; r < 4; ++r) {
            int row = start + mt * 16 + lg * 4 + r;
            row = (row > nsum - 1) ? (nsum - 1) : row;   // pad rows: masked later
            const float* p = &Hp[(size_t)row * N_REL + T * 16 + nl15];
            gv[mt][r] = (p[0] + p[(size_t)hstride])
                      + (p[(size_t)hstride * 2] + p[(size_t)hstride * 3]);
        }

    // ---- in-register masked softmax over m (validated r5-r11) ----
    float vmax = -INFINITY;
    #pragma unroll
    for (int mt = 0; mt < 2; ++mt)
        #pragma unroll
        for (int r = 0; r < 4; ++r) {
            const int m = mt * 16 + lg * 4 + r;
            if (m < size) vmax = fmaxf(vmax, gv[mt][r]);
        }
    vmax = fmaxf(vmax, __shfl_xor(vmax, 16));
    vmax = fmaxf(vmax, __shfl_xor(vmax, 32));

    float ssum = 0.f;
    #pragma unroll
    for (int mt = 0; mt < 2; ++mt)
        #pragma unroll
        for (int r = 0; r < 4; ++r) {
            const int m = mt * 16 + lg * 4 + r;
            float e = (m < size) ? __expf(gv[mt][r] - vmax) : 0.f;
            smv[mt][r] = e;
            ssum += e;
        }
    ssum += __shfl_xor(ssum, 16);
    ssum += __shfl_xor(ssum, 32);
    const float inv = 1.f / ssum;
    #pragma unroll
    for (int mt = 0; mt < 2; ++mt)
        #pragma unroll
        for (int r = 0; r < 4; ++r) smv[mt][r] *= inv;

    // ---- scatter to frag layouts (validated r4-r11) ----
    #pragma unroll
    for (int mt = 0; mt < 2; ++mt)
        #pragma unroll
        for (int rp = 0; rp < 4; rp += 2) {
            const int m     = mt * 16 + lg * 4 + rp;
            const int lane2 = (m >> 3) * 16 + nl15;
            const int word  = (m >> 1) & 3;
            const int ihi = ((T * 2 + 0) * 64 + lane2) * 4 + word;
            const int ilo = ((T * 2 + 1) * 64 + lane2) * 4 + word;
            Gfrag[ihi]  = pack_hi(gv[mt][rp], gv[mt][rp + 1]);
            Gfrag[ilo]  = pack_hi(trunc_res(gv[mt][rp]), trunc_res(gv[mt][rp + 1]));
            SMfrag[ihi] = pack_hi(smv[mt][rp], smv[mt][rp + 1]);
            SMfrag[ilo] = pack_hi(trunc_res(smv[mt][rp]), trunc_res(smv[mt][rp + 1]));
        }
    __syncthreads();   // the only barrier

    // ---- Phase 2: row-tile T of full = SM @ G (validated r6-r11) ----
    float bias_r[8];
    #pragma unroll
    for (int ct = 0; ct < 8; ++ct) bias_r[ct] = bias[ct * 16 + nl15];

    f32x4 facc[8];
    #pragma unroll
    for (int ct = 0; ct < 8; ++ct) facc[ct] = f32x4{0.f, 0.f, 0.f, 0.f};

    const bf16x8 ah2 = *(const bf16x8*)&SMfrag[((T * 2 + 0) * 64 + lane) * 4];
    const bf16x8 al2 = *(const bf16x8*)&SMfrag[((T * 2 + 1) * 64 + lane) * 4];
    #pragma unroll
    for (int ct = 0; ct < 8; ++ct) {
        const bf16x8 bh = *(const bf16x8*)&Gfrag[((ct * 2 + 0) * 64 + lane) * 4];
        const bf16x8 bl = *(const bf16x8*)&Gfrag[((ct * 2 + 1) * 64 + lane) * 4];
        facc[ct] = __builtin_amdgcn_mfma_f32_16x16x32_bf16(ah2, bh, facc[ct], 0, 0, 0);
        facc[ct] = __builtin_amdgcn_mfma_f32_16x16x32_bf16(ah2, bl, facc[ct], 0, 0, 0);
        facc[ct] = __builtin_amdgcn_mfma_f32_16x16x32_bf16(al2, bh, facc[ct], 0, 0, 0);
    }

    // ---- in-register row softmax over k + diagonal -> out (validated) ----
    #pragma unroll
    for (int r = 0; r < 4; ++r) {
        float s[8];
        #pragma unroll
        for (int ct = 0; ct < 8; ++ct) s[ct] = facc[ct][r] + bias_r[ct];

        float mx = s[0];
        #pragma unroll
        for (int ct = 1; ct < 8; ++ct) mx = fmaxf(mx, s[ct]);
        mx = fmaxf(mx, __shfl_xor(mx, 1));
        mx = fmaxf(mx, __shfl_xor(mx, 2));
        mx = fmaxf(mx, __shfl_xor(mx, 4));
        mx = fmaxf(mx, __shfl_xor(mx, 8));

        float l = 0.f;
        #pragma unroll
        for (int ct = 0; ct < 8; ++ct) l += __expf(s[ct] - mx);
        l += __shfl_xor(l, 1);
        l += __shfl_xor(l, 2);
        l += __shfl_xor(l, 4);
        l += __shfl_xor(l, 8);

        const int nl = lg * 4 + r;
        float sd = s[0];
        #pragma unroll
        for (int ct = 1; ct < 8; ++ct) sd = (ct == T) ? s[ct] : sd;
        if (nl15 == nl) {
            out[b * N_REL + T * 16 + nl] = __expf(sd - mx) / l;
        }
    }
}

// ---------------------------------------------------------------------------
extern "C" void kernel_launch(void* const* d_in, const int* in_sizes, int n_in,
                              void* d_out, int out_size, void* d_ws, size_t ws_size,
                              hipStream_t stream) {
    const float* rep   = (const float*)d_in[0];
    const float* W     = (const float*)d_in[1];
    const float* bias  = (const float*)d_in[2];
    const int*   scope = (const int*)d_in[3];

    const int nsum    = in_sizes[0] / D_DIM;
    const int strips  = (nsum + 31) >> 5;
    const int hstride = strips * 32 * N_REL;    // floats per partial buffer

    unsigned* Bfrag = (unsigned*)d_ws;                    // 393216 B
    float*    Hp    = (float*)((char*)d_ws + 393216);     // NCHUNK * hstride

    build_bfrag<<<48, 256, 0, stream>>>(W, Bfrag);
    h_gemm<<<dim3(strips, NCHUNK), 256, 0, stream>>>(rep, Bfrag, Hp, nsum, hstride);
    bag_out<<<B_BAGS, 512, 0, stream>>>(Hp, hstride, bias, scope,
                                        (float*)d_out, nsum);
}

// Round 13
// 94.558 us; speedup vs baseline: 1.0088x; 1.0088x over previous
//
#include <hip/hip_runtime.h>
#include <math.h>

#define B_BAGS 512
#define N_REL  128
#define D_DIM  768

typedef __attribute__((ext_vector_type(8))) short  bf16x8;
typedef __attribute__((ext_vector_type(4))) float  f32x4;

// pack truncated-bf16 of (f0,f1) -> one uint (low short = bf16(f0))
__device__ inline unsigned pack_hi(float f0, float f1) {
    return __builtin_amdgcn_perm(__float_as_uint(f1), __float_as_uint(f0), 0x07060302u);
}
__device__ inline float trunc_res(float f) {   // f - bf16_trunc(f)
    return f - __uint_as_float(__float_as_uint(f) & 0xFFFF0000u);
}

// ---------------------------------------------------------------------------
// K1: fragment-ordered bf16 hi/lo of W (validated r2-r12).
// uint index = ((s*8 + tile)*2 + p)*256 + lane*4 + 0..3
// Element: n = tile*16 + (lane&15), k = s*32 + (lane>>4)*8 + j.
// ---------------------------------------------------------------------------
__global__ void build_bfrag(const float* __restrict__ W, unsigned* __restrict__ Bfrag) {
    int flat = blockIdx.x * 256 + threadIdx.x;     // 0..12287
    int lane = flat & 63;
    int tile = (flat >> 6) & 7;
    int s    = flat >> 9;                          // 0..23
    int n  = tile * 16 + (lane & 15);
    int k0 = s * 32 + (lane >> 4) * 8;
    const float* src = &W[n * D_DIM + k0];
    float f[8];
    #pragma unroll
    for (int j = 0; j < 8; ++j) f[j] = src[j];
    unsigned hi[4], lo[4];
    #pragma unroll
    for (int q = 0; q < 4; ++q) {
        hi[q] = pack_hi(f[2*q], f[2*q+1]);
        lo[q] = pack_hi(trunc_res(f[2*q]), trunc_res(f[2*q+1]));
    }
    unsigned base = (unsigned)(((s * 8 + tile) * 2) * 64 + lane) * 4;
    *(uint4*)&Bfrag[base]          = make_uint4(hi[0], hi[1], hi[2], hi[3]);
    *(uint4*)&Bfrag[base + 64 * 4] = make_uint4(lo[0], lo[1], lo[2], lo[3]);
}

// ---------------------------------------------------------------------------
// K2: dense H = rep @ W^T, 16-row strips x split-K/2 (R11 traffic shape),
// but 512 thr = 8 waves, ONE n-tile per wave (3 MFMA/gs on 2 B-loads).
// ~1054 blocks x 8 waves, 8.8 KB LDS -> ~4 blocks/CU = 32 waves/CU.
// A staged per-128-k chunk as packed bf16 hi/lo (stride-68 pad, 2-way free).
// B direct from L2-resident Bfrag. Plain stores to partial Hp[chunk].
// ---------------------------------------------------------------------------
__global__ __launch_bounds__(512, 4) void h_gemm(
    const float*    __restrict__ rep,
    const unsigned* __restrict__ Bfrag,
    float*          __restrict__ Hp,     // 2 buffers of hstride floats
    int nsum, int hstride)
{
    __shared__ unsigned As[2][16][68];   // [plane][row][64+4 pad]  8.7 KB

    const int t     = threadIdx.x;
    const int strip = blockIdx.x;
    const int chunk = blockIdx.y;        // K-half (12 gs each)

    const int wv   = t >> 6;             // 0..7 = owned n-tile
    const int lane = t & 63;
    const int nl15 = lane & 15;
    const int lg   = lane >> 4;

    // staging: thread covers row t>>5, float4 at (t&31)*4 of each 128-k chunk
    const int srow = t >> 5;
    const int scq  = t & 31;
    int grow = strip * 16 + srow;
    grow = (grow > nsum - 1) ? (nsum - 1) : grow;
    const float* srp = &rep[(size_t)grow * D_DIM + chunk * 384 + scq * 4];

    f32x4 acc0 = f32x4{0.f, 0.f, 0.f, 0.f};   // hi*hi
    f32x4 acc1 = f32x4{0.f, 0.f, 0.f, 0.f};   // hi*lo + lo*hi

    #pragma unroll
    for (int st = 0; st < 3; ++st) {
        if (st) __syncthreads();         // previous chunk's reads complete
        // ---- stage 128 k-cols: fp32 -> bf16 hi/lo into LDS ----
        {
            const float4 v = *(const float4*)&srp[st * 128];
            const unsigned h0 = pack_hi(v.x, v.y);
            const unsigned h1 = pack_hi(v.z, v.w);
            const unsigned l0 = pack_hi(trunc_res(v.x), trunc_res(v.y));
            const unsigned l1 = pack_hi(trunc_res(v.z), trunc_res(v.w));
            *(uint2*)&As[0][srow][scq * 2] = make_uint2(h0, h1);
            *(uint2*)&As[1][srow][scq * 2] = make_uint2(l0, l1);
        }
        __syncthreads();

        // ---- compute 4 gs of this chunk ----
        #pragma unroll
        for (int g = 0; g < 4; ++g) {
            const int gs = chunk * 12 + st * 4 + g;       // global K-step 0..23
            const bf16x8 ah = *(const bf16x8*)&As[0][nl15][g * 16 + lg * 4];
            const bf16x8 al = *(const bf16x8*)&As[1][nl15][g * 16 + lg * 4];
            const bf16x8 bh = *(const bf16x8*)&Bfrag[((gs * 8 + wv) * 2 + 0) * 256 + lane * 4];
            const bf16x8 bl = *(const bf16x8*)&Bfrag[((gs * 8 + wv) * 2 + 1) * 256 + lane * 4];
            acc0 = __builtin_amdgcn_mfma_f32_16x16x32_bf16(ah, bh, acc0, 0, 0, 0);
            acc1 = __builtin_amdgcn_mfma_f32_16x16x32_bf16(ah, bl, acc1, 0, 0, 0);
            acc1 = __builtin_amdgcn_mfma_f32_16x16x32_bf16(al, bh, acc1, 0, 0, 0);
        }
    }

    // ---- epilogue: C/D layout col=lane&15, row=(lane>>4)*4+r (validated) ----
    float* H = Hp + (size_t)chunk * hstride;
    const int rowb = strip * 16 + lg * 4;
    const int col  = wv * 16 + nl15;
    #pragma unroll
    for (int r = 0; r < 4; ++r)
        H[(size_t)(rowb + r) * N_REL + col] = acc0[r] + acc1[r];
}

// ---------------------------------------------------------------------------
// K3: per-bag output (R11 verbatim). 512 thr = 8 waves; wave T = wv owns
// n-tile T. gv = sum of 2 Hp partials in C/D-register positions, then the
// r5-r12-validated tail: in-register masked softmax over m, frag scatter,
// 24-MFMA phase 2, in-register row softmax over k, diagonal -> out.
// ---------------------------------------------------------------------------
__global__ __launch_bounds__(512, 2) void bag_out(
    const float* __restrict__ Hp, int hstride,
    const float* __restrict__ bias,
    const int*   __restrict__ scope,
    float*       __restrict__ out,
    int nsum)
{
    __shared__ unsigned Gfrag[8 * 2 * 64 * 4];    // 16 KB [tile][p][lane][4]
    __shared__ unsigned SMfrag[8 * 2 * 64 * 4];   // 16 KB

    const int t = threadIdx.x;
    const int b = blockIdx.x;
    const int start = scope[2 * b];
    const int size  = scope[2 * b + 1] - start;   // in [8, 25)

    const int wv   = t >> 6;
    const int lane = t & 63;
    const int nl15 = lane & 15;
    const int lg   = lane >> 4;
    const int T    = wv;

    // ---- gv: sum of 2 partials in C/D positions ----
    float gv[2][4], smv[2][4];
    #pragma unroll
    for (int mt = 0; mt < 2; ++mt)
        #pragma unroll
        for (int r = 0; r < 4; ++r) {
            int row = start + mt * 16 + lg * 4 + r;
            row = (row > nsum - 1) ? (nsum - 1) : row;   // pad rows: masked later
            const float* p = &Hp[(size_t)row * N_REL + T * 16 + nl15];
            gv[mt][r] = p[0] + p[(size_t)hstride];
        }

    // ---- in-register masked softmax over m (validated r5-r12) ----
    float vmax = -INFINITY;
    #pragma unroll
    for (int mt = 0; mt < 2; ++mt)
        #pragma unroll
        for (int r = 0; r < 4; ++r) {
            const int m = mt * 16 + lg * 4 + r;
            if (m < size) vmax = fmaxf(vmax, gv[mt][r]);
        }
    vmax = fmaxf(vmax, __shfl_xor(vmax, 16));
    vmax = fmaxf(vmax, __shfl_xor(vmax, 32));

    float ssum = 0.f;
    #pragma unroll
    for (int mt = 0; mt < 2; ++mt)
        #pragma unroll
        for (int r = 0; r < 4; ++r) {
            const int m = mt * 16 + lg * 4 + r;
            float e = (m < size) ? __expf(gv[mt][r] - vmax) : 0.f;
            smv[mt][r] = e;
            ssum += e;
        }
    ssum += __shfl_xor(ssum, 16);
    ssum += __shfl_xor(ssum, 32);
    const float inv = 1.f / ssum;
    #pragma unroll
    for (int mt = 0; mt < 2; ++mt)
        #pragma unroll
        for (int r = 0; r < 4; ++r) smv[mt][r] *= inv;

    // ---- scatter to frag layouts (validated r4-r12) ----
    #pragma unroll
    for (int mt = 0; mt < 2; ++mt)
        #pragma unroll
        for (int rp = 0; rp < 4; rp += 2) {
            const int m     = mt * 16 + lg * 4 + rp;
            const int lane2 = (m >> 3) * 16 + nl15;
            const int word  = (m >> 1) & 3;
            const int ihi = ((T * 2 + 0) * 64 + lane2) * 4 + word;
            const int ilo = ((T * 2 + 1) * 64 + lane2) * 4 + word;
            Gfrag[ihi]  = pack_hi(gv[mt][rp], gv[mt][rp + 1]);
            Gfrag[ilo]  = pack_hi(trunc_res(gv[mt][rp]), trunc_res(gv[mt][rp + 1]));
            SMfrag[ihi] = pack_hi(smv[mt][rp], smv[mt][rp + 1]);
            SMfrag[ilo] = pack_hi(trunc_res(smv[mt][rp]), trunc_res(smv[mt][rp + 1]));
        }
    __syncthreads();   // the only barrier

    // ---- Phase 2: row-tile T of full = SM @ G (validated r6-r12) ----
    float bias_r[8];
    #pragma unroll
    for (int ct = 0; ct < 8; ++ct) bias_r[ct] = bias[ct * 16 + nl15];

    f32x4 facc[8];
    #pragma unroll
    for (int ct = 0; ct < 8; ++ct) facc[ct] = f32x4{0.f, 0.f, 0.f, 0.f};

    const bf16x8 ah2 = *(const bf16x8*)&SMfrag[((T * 2 + 0) * 64 + lane) * 4];
    const bf16x8 al2 = *(const bf16x8*)&SMfrag[((T * 2 + 1) * 64 + lane) * 4];
    #pragma unroll
    for (int ct = 0; ct < 8; ++ct) {
        const bf16x8 bh = *(const bf16x8*)&Gfrag[((ct * 2 + 0) * 64 + lane) * 4];
        const bf16x8 bl = *(const bf16x8*)&Gfrag[((ct * 2 + 1) * 64 + lane) * 4];
        facc[ct] = __builtin_amdgcn_mfma_f32_16x16x32_bf16(ah2, bh, facc[ct], 0, 0, 0);
        facc[ct] = __builtin_amdgcn_mfma_f32_16x16x32_bf16(ah2, bl, facc[ct], 0, 0, 0);
        facc[ct] = __builtin_amdgcn_mfma_f32_16x16x32_bf16(al2, bh, facc[ct], 0, 0, 0);
    }

    // ---- in-register row softmax over k + diagonal -> out (validated) ----
    #pragma unroll
    for (int r = 0; r < 4; ++r) {
        float s[8];
        #pragma unroll
        for (int ct = 0; ct < 8; ++ct) s[ct] = facc[ct][r] + bias_r[ct];

        float mx = s[0];
        #pragma unroll
        for (int ct = 1; ct < 8; ++ct) mx = fmaxf(mx, s[ct]);
        mx = fmaxf(mx, __shfl_xor(mx, 1));
        mx = fmaxf(mx, __shfl_xor(mx, 2));
        mx = fmaxf(mx, __shfl_xor(mx, 4));
        mx = fmaxf(mx, __shfl_xor(mx, 8));

        float l = 0.f;
        #pragma unroll
        for (int ct = 0; ct < 8; ++ct) l += __expf(s[ct] - mx);
        l += __shfl_xor(l, 1);
        l += __shfl_xor(l, 2);
        l += __shfl_xor(l, 4);
        l += __shfl_xor(l, 8);

        const int nl = lg * 4 + r;
        float sd = s[0];
        #pragma unroll
        for (int ct = 1; ct < 8; ++ct) sd = (ct == T) ? s[ct] : sd;
        if (nl15 == nl) {
            out[b * N_REL + T * 16 + nl] = __expf(sd - mx) / l;
        }
    }
}

// ---------------------------------------------------------------------------
extern "C" void kernel_launch(void* const* d_in, const int* in_sizes, int n_in,
                              void* d_out, int out_size, void* d_ws, size_t ws_size,
                              hipStream_t stream) {
    const float* rep   = (const float*)d_in[0];
    const float* W     = (const float*)d_in[1];
    const float* bias  = (const float*)d_in[2];
    const int*   scope = (const int*)d_in[3];

    const int nsum    = in_sizes[0] / D_DIM;
    const int strips  = (nsum + 15) >> 4;
    const int hstride = strips * 16 * N_REL;    // floats per partial buffer

    unsigned* Bfrag = (unsigned*)d_ws;                    // 393216 B
    float*    Hp    = (float*)((char*)d_ws + 393216);     // 2 * hstride fp32

    build_bfrag<<<48, 256, 0, stream>>>(W, Bfrag);
    h_gemm<<<dim3(strips, 2), 512, 0, stream>>>(rep, Bfrag, Hp, nsum, hstride);
    bag_out<<<B_BAGS, 512, 0, stream>>>(Hp, hstride, bias, scope,
                                        (float*)d_out, nsum);
}